// Round 1
// baseline (516.781 us; speedup 1.0000x reference)
//
#include <hip/hip_runtime.h>
#include <hip/hip_bf16.h>

#define S 2048
#define D 180
#define H 18
#define DKH 10
#define F 720
#define V 50257
#define VP 50304   // V padded to multiple of 128
#define KP 192     // D padded to multiple of 32
#define EPS 1e-5f

typedef __attribute__((ext_vector_type(8))) short bf16x8;
typedef __attribute__((ext_vector_type(4))) float f32x4;

// ---------------- Wo -> bf16 padded [VP][KP] ----------------
__global__ void k_wbconv(const float* __restrict__ Wo, __hip_bfloat16* __restrict__ wb) {
    int idx = blockIdx.x * 256 + threadIdx.x;
    const int total = VP * KP;
    if (idx >= total) return;
    int n = idx / KP;
    int k = idx - n * KP;
    float v = 0.0f;
    if (n < V && k < D) v = Wo[n * D + k];
    wb[idx] = __float2bfloat16(v);
}

// ---------------- embedding + positional encoding ----------------
__global__ void k_embed(const int* __restrict__ ids, const float* __restrict__ emb,
                        float* __restrict__ x0) {
    int s = blockIdx.x;
    int d = threadIdx.x;
    if (d >= D) return;
    int i = d >> 1;
    double inv = pow(10000.0, -(double)i / 90.0);
    double ang = (double)s * inv;
    float pe = (d & 1) ? (float)cos(ang) : (float)sin(ang);
    x0[s * D + d] = emb[(long)ids[s] * D + d] + pe;
}

// ---------------- QKV projections ----------------
__global__ void k_qkv(const float* __restrict__ x0, const float* __restrict__ Wq,
                      const float* __restrict__ Wk, const float* __restrict__ Wv,
                      float* __restrict__ qkv) {
    const int R = 8;
    __shared__ float xs[R * D];
    int r0 = blockIdx.x * R;
    const float* W = (blockIdx.y == 0) ? Wq : ((blockIdx.y == 1) ? Wk : Wv);
    float* out = qkv + blockIdx.y * (S * D);
    for (int idx = threadIdx.x; idx < R * D; idx += blockDim.x)
        xs[idx] = x0[r0 * D + idx];
    __syncthreads();
    int d = threadIdx.x;
    if (d < D) {
        float acc[R];
        #pragma unroll
        for (int r = 0; r < R; ++r) acc[r] = 0.0f;
        for (int k = 0; k < D; ++k) {
            float w = W[d * D + k];
            #pragma unroll
            for (int r = 0; r < R; ++r) acc[r] += xs[r * D + k] * w;
        }
        #pragma unroll
        for (int r = 0; r < R; ++r) out[(r0 + r) * D + d] = acc[r];
    }
}

// ---------------- causal attention (flash-style, f32) ----------------
__global__ __launch_bounds__(512) void k_attn(const float* __restrict__ qkv,
                                              float* __restrict__ ao) {
    __shared__ float Ks[128][12];
    __shared__ float Vs[128][12];
    __shared__ float cmb[64][8][12];
    int h = blockIdx.y;
    int q0 = blockIdx.x * 64;
    int t = threadIdx.x;
    int i = t & 63, w = t >> 6;
    int qi = q0 + i;
    const float* qp = qkv + qi * D + h * DKH;
    const float* kp = qkv + S * D + h * DKH;
    const float* vp = qkv + 2 * S * D + h * DKH;
    float qv[DKH];
    #pragma unroll
    for (int c = 0; c < DKH; ++c) qv[c] = qp[c];
    float m = -INFINITY, l = 0.0f, acc[DKH] = {};
    const float scale = 0.31622776601683794f;  // 1/sqrt(10)
    int ntiles = (q0 + 64 + 127) >> 7;
    for (int tile = 0; tile < ntiles; ++tile) {
        int j0 = tile << 7;
        __syncthreads();
        for (int idx = t; idx < 128 * DKH; idx += 512) {
            int jj = idx / DKH, c = idx - jj * DKH;
            Ks[jj][c] = kp[(j0 + jj) * D + c];
            Vs[jj][c] = vp[(j0 + jj) * D + c];
        }
        __syncthreads();
        float sv[16], tmax = -INFINITY;
        #pragma unroll
        for (int u = 0; u < 16; ++u) {
            int jj = w * 16 + u;
            float dacc = 0.0f;
            #pragma unroll
            for (int c = 0; c < DKH; ++c) dacc += qv[c] * Ks[jj][c];
            dacc *= scale;
            sv[u] = (j0 + jj <= qi) ? dacc : -INFINITY;
            tmax = fmaxf(tmax, sv[u]);
        }
        if (tmax > -INFINITY) {
            float nm = fmaxf(m, tmax);
            float cor = __expf(m - nm);
            l *= cor;
            #pragma unroll
            for (int c = 0; c < DKH; ++c) acc[c] *= cor;
            m = nm;
            #pragma unroll
            for (int u = 0; u < 16; ++u) {
                float p = __expf(sv[u] - m);
                int jj = w * 16 + u;
                l += p;
                #pragma unroll
                for (int c = 0; c < DKH; ++c) acc[c] += p * Vs[jj][c];
            }
        }
    }
    cmb[i][w][0] = m;
    cmb[i][w][1] = l;
    #pragma unroll
    for (int c = 0; c < DKH; ++c) cmb[i][w][2 + c] = acc[c];
    __syncthreads();
    if (t < 64) {
        float M = -INFINITY;
        for (int ww = 0; ww < 8; ++ww) M = fmaxf(M, cmb[t][ww][0]);
        float L = 0.0f, o[DKH] = {};
        for (int ww = 0; ww < 8; ++ww) {
            float e = __expf(cmb[t][ww][0] - M);
            L += e * cmb[t][ww][1];
            #pragma unroll
            for (int c = 0; c < DKH; ++c) o[c] += e * cmb[t][ww][2 + c];
        }
        float inv = 1.0f / L;
        float* op = ao + (q0 + t) * D + h * DKH;
        #pragma unroll
        for (int c = 0; c < DKH; ++c) op[c] = o[c] * inv;
    }
}

// ---------------- wave helpers ----------------
__device__ inline float wave_sum(float v) {
    #pragma unroll
    for (int o = 32; o > 0; o >>= 1) v += __shfl_xor(v, o);
    return v;
}

// ---------------- LayerNorm 1: x1 = LN(x0 + ao)*g + b ----------------
__global__ void k_ln1(const float* __restrict__ x0, const float* __restrict__ ao,
                      const float* __restrict__ g, const float* __restrict__ b,
                      float* __restrict__ x1) {
    int row = blockIdx.x * 4 + (threadIdx.x >> 6);
    int lane = threadIdx.x & 63;
    const float* pa = x0 + row * D;
    const float* pb = ao + row * D;
    float v[3];
    int c[3];
    float sum = 0.0f;
    #pragma unroll
    for (int k = 0; k < 3; ++k) {
        c[k] = lane + 64 * k;
        v[k] = (c[k] < D) ? (pa[c[k]] + pb[c[k]]) : 0.0f;
        sum += v[k];
    }
    sum = wave_sum(sum);
    float mu = sum / (float)D;
    float ss = 0.0f;
    #pragma unroll
    for (int k = 0; k < 3; ++k) {
        float dd = (c[k] < D) ? (v[k] - mu) : 0.0f;
        ss += dd * dd;
    }
    ss = wave_sum(ss);
    float rs = rsqrtf(ss / (float)D + EPS);
    #pragma unroll
    for (int k = 0; k < 3; ++k)
        if (c[k] < D) x1[row * D + c[k]] = (v[k] - mu) * rs * g[c[k]] + b[c[k]];
}

// ---------------- FFN1: y = gelu(x1 @ W1^T + bf1) ----------------
__global__ void k_ffn1(const float* __restrict__ x1, const float* __restrict__ W1,
                       const float* __restrict__ bf1, float* __restrict__ y) {
    const int R = 16;
    __shared__ float xs[R * D];
    int r0 = blockIdx.y * R;
    int f = blockIdx.x * 256 + threadIdx.x;
    for (int idx = threadIdx.x; idx < R * D; idx += 256)
        xs[idx] = x1[r0 * D + idx];
    __syncthreads();
    if (f < F) {
        float acc[R] = {};
        for (int k = 0; k < D; ++k) {
            float wv = W1[f * D + k];
            #pragma unroll
            for (int r = 0; r < R; ++r) acc[r] += xs[r * D + k] * wv;
        }
        float bb = bf1[f];
        #pragma unroll
        for (int r = 0; r < R; ++r) {
            float vv = acc[r] + bb;
            float gg = 0.5f * vv * (1.0f + erff(vv * 0.7071067811865475f));
            y[(r0 + r) * F + f] = gg;
        }
    }
}

// ---------------- FFN2: z = x1 + y @ W2^T + bf2 ----------------
__global__ void k_ffn2(const float* __restrict__ y, const float* __restrict__ W2,
                       const float* __restrict__ bf2, const float* __restrict__ x1,
                       float* __restrict__ z) {
    const int R = 4;
    __shared__ float ys[R * F];
    int r0 = blockIdx.x * R;
    for (int idx = threadIdx.x; idx < R * F; idx += 192)
        ys[idx] = y[r0 * F + idx];
    __syncthreads();
    int d = threadIdx.x;
    if (d < D) {
        float acc[R] = {};
        for (int k = 0; k < F; ++k) {
            float wv = W2[d * F + k];
            #pragma unroll
            for (int r = 0; r < R; ++r) acc[r] += ys[r * F + k] * wv;
        }
        #pragma unroll
        for (int r = 0; r < R; ++r)
            z[(r0 + r) * D + d] = x1[(r0 + r) * D + d] + acc[r] + bf2[d];
    }
}

// ---------------- LayerNorm 2 -> bf16 padded [S][KP] ----------------
__global__ void k_ln2(const float* __restrict__ z, const float* __restrict__ g,
                      const float* __restrict__ b, __hip_bfloat16* __restrict__ xb) {
    int row = blockIdx.x * 4 + (threadIdx.x >> 6);
    int lane = threadIdx.x & 63;
    const float* pz = z + row * D;
    float v[3];
    int c[3];
    float sum = 0.0f;
    #pragma unroll
    for (int k = 0; k < 3; ++k) {
        c[k] = lane + 64 * k;
        v[k] = (c[k] < D) ? pz[c[k]] : 0.0f;
        sum += v[k];
    }
    sum = wave_sum(sum);
    float mu = sum / (float)D;
    float ss = 0.0f;
    #pragma unroll
    for (int k = 0; k < 3; ++k) {
        float dd = (c[k] < D) ? (v[k] - mu) : 0.0f;
        ss += dd * dd;
    }
    ss = wave_sum(ss);
    float rs = rsqrtf(ss / (float)D + EPS);
    #pragma unroll
    for (int k = 0; k < 3; ++k) {
        float outv = (c[k] < D) ? ((v[k] - mu) * rs * g[c[k]] + b[c[k]]) : 0.0f;
        xb[row * KP + c[k]] = __float2bfloat16(outv);
    }
}

// ---------------- logits GEMM: out = xb @ wb^T + bo ----------------
// grid 6288 = 16 (M/128) * 393 (VP/128); block 256 = 4 waves (2x2), 64x64 per wave
__global__ void k_logits(const __hip_bfloat16* __restrict__ xbp,
                         const __hip_bfloat16* __restrict__ wbp,
                         const float* __restrict__ bo, float* __restrict__ out) {
    int Lb = blockIdx.x;
    int wg = (Lb & 7) * 786 + (Lb >> 3);   // bijective XCD swizzle (6288 = 8*786)
    int mblk = wg & 15;
    int pblk = wg >> 4;
    int m0 = mblk * 128, n0 = pblk * 128;
    int t = threadIdx.x;
    int lane = t & 63, wid = t >> 6;
    int wy = wid >> 1, wx = wid & 1;
    int r16 = lane & 15, kgrp = lane >> 4;
    const short* xs = (const short*)xbp;
    const short* ws = (const short*)wbp;
    f32x4 acc[4][4] = {};
    int arow[4], brow[4];
    #pragma unroll
    for (int mi = 0; mi < 4; ++mi) arow[mi] = m0 + wy * 64 + mi * 16 + r16;
    #pragma unroll
    for (int ni = 0; ni < 4; ++ni) brow[ni] = n0 + wx * 64 + ni * 16 + r16;
    #pragma unroll
    for (int kk = 0; kk < 6; ++kk) {
        int kb = kk * 32 + kgrp * 8;
        bf16x8 a[4], b[4];
        #pragma unroll
        for (int mi = 0; mi < 4; ++mi)
            a[mi] = *(const bf16x8*)(xs + arow[mi] * KP + kb);
        #pragma unroll
        for (int ni = 0; ni < 4; ++ni)
            b[ni] = *(const bf16x8*)(ws + brow[ni] * KP + kb);
        #pragma unroll
        for (int mi = 0; mi < 4; ++mi)
            #pragma unroll
            for (int ni = 0; ni < 4; ++ni)
                acc[mi][ni] = __builtin_amdgcn_mfma_f32_16x16x32_bf16(a[mi], b[ni], acc[mi][ni], 0, 0, 0);
    }
    #pragma unroll
    for (int ni = 0; ni < 4; ++ni) {
        int col = brow[ni];
        float bias = (col < V) ? bo[col] : 0.0f;
        #pragma unroll
        for (int mi = 0; mi < 4; ++mi) {
            int rbase = m0 + wy * 64 + mi * 16 + kgrp * 4;
            #pragma unroll
            for (int j = 0; j < 4; ++j) {
                if (col < V) out[(rbase + j) * V + col] = acc[mi][ni][j] + bias;
            }
        }
    }
}

extern "C" void kernel_launch(void* const* d_in, const int* in_sizes, int n_in,
                              void* d_out, int out_size, void* d_ws, size_t ws_size,
                              hipStream_t stream) {
    const int* ids   = (const int*)d_in[0];
    const float* emb = (const float*)d_in[1];
    const float* Wq  = (const float*)d_in[2];
    const float* Wk  = (const float*)d_in[3];
    const float* Wv  = (const float*)d_in[4];
    const float* g1  = (const float*)d_in[5];
    const float* b1  = (const float*)d_in[6];
    const float* W1  = (const float*)d_in[7];
    const float* bf1 = (const float*)d_in[8];
    const float* W2  = (const float*)d_in[9];
    const float* bf2 = (const float*)d_in[10];
    const float* g2  = (const float*)d_in[11];
    const float* b2  = (const float*)d_in[12];
    const float* Wo  = (const float*)d_in[13];
    const float* bo  = (const float*)d_in[14];
    float* out = (float*)d_out;

    char* w = (char*)d_ws;
    float* x0 = (float*)w;           w += S * D * 4;
    float* qkv = (float*)w;          w += 3 * S * D * 4;
    float* ao = (float*)w;           w += S * D * 4;
    float* x1 = (float*)w;           w += S * D * 4;
    float* y = (float*)w;            w += S * F * 4;
    float* z = (float*)w;            w += S * D * 4;
    __hip_bfloat16* xb = (__hip_bfloat16*)w; w += S * KP * 2;
    __hip_bfloat16* wb = (__hip_bfloat16*)w; w += (size_t)VP * KP * 2;

    k_wbconv<<<dim3((VP * KP + 255) / 256), 256, 0, stream>>>(Wo, wb);
    k_embed<<<dim3(S), 192, 0, stream>>>(ids, emb, x0);
    k_qkv<<<dim3(S / 8, 3), 192, 0, stream>>>(x0, Wq, Wk, Wv, qkv);
    k_attn<<<dim3(32, H), 512, 0, stream>>>(qkv, ao);
    k_ln1<<<dim3(S / 4), 256, 0, stream>>>(x0, ao, g1, b1, x1);
    k_ffn1<<<dim3(3, S / 16), 256, 0, stream>>>(x1, W1, bf1, y);
    k_ffn2<<<dim3(S / 4), 192, 0, stream>>>(y, W2, bf2, x1, z);
    k_ln2<<<dim3(S / 4), 256, 0, stream>>>(z, g2, b2, xb);
    k_logits<<<dim3(6288), 256, 0, stream>>>(xb, wb, bo, out);
}

// Round 3
// 515.504 us; speedup vs baseline: 1.0025x; 1.0025x over previous
//
#include <hip/hip_runtime.h>
#include <hip/hip_bf16.h>

#define S 2048
#define D 180
#define H 18
#define DKH 10
#define F 720
#define V 50257
#define VP 50304   // V padded to multiple of 128
#define KP 192     // D padded to multiple of 32
#define EPS 1e-5f

typedef __attribute__((ext_vector_type(8))) short bf16x8;
typedef __attribute__((ext_vector_type(4))) float f32x4;

// ---------------- Wo -> bf16 padded [VP][KP], 8 elems/thread ----------------
__global__ void k_wbconv(const float* __restrict__ Wo, __hip_bfloat16* __restrict__ wb) {
    int idx = blockIdx.x * 256 + threadIdx.x;
    const int total = VP * 24;               // KP/8 = 24 chunks per row
    if (idx >= total) return;
    int n = idx / 24;
    int k0 = (idx - n * 24) * 8;
    __hip_bfloat16 tmp[8];
    #pragma unroll
    for (int j = 0; j < 8; ++j) {
        int k = k0 + j;
        float v = (n < V && k < D) ? Wo[n * D + k] : 0.0f;
        tmp[j] = __float2bfloat16(v);
    }
    *(bf16x8*)((short*)wb + n * KP + k0) = *(bf16x8*)tmp;
}

// ---------------- embedding + positional encoding (float math) ----------------
__global__ void k_embed(const int* __restrict__ ids, const float* __restrict__ emb,
                        float* __restrict__ x0) {
    int s = blockIdx.x;
    int d = threadIdx.x;
    if (d >= D) return;
    int i = d >> 1;
    float inv = exp2f(-0.14764124866166054f * (float)i);  // 10000^(-i/90)
    float ang = (float)s * inv;
    float pe = (d & 1) ? cosf(ang) : sinf(ang);
    x0[s * D + d] = emb[(long)ids[s] * D + d] + pe;
}

// ---------------- QKV projections ----------------
__global__ void k_qkv(const float* __restrict__ x0, const float* __restrict__ Wq,
                      const float* __restrict__ Wk, const float* __restrict__ Wv,
                      float* __restrict__ qkv) {
    const int R = 8;
    __shared__ float xs[R * D];
    int r0 = blockIdx.x * R;
    const float* W = (blockIdx.y == 0) ? Wq : ((blockIdx.y == 1) ? Wk : Wv);
    float* out = qkv + blockIdx.y * (S * D);
    for (int idx = threadIdx.x; idx < R * D; idx += blockDim.x)
        xs[idx] = x0[r0 * D + idx];
    __syncthreads();
    int d = threadIdx.x;
    if (d < D) {
        float acc[R];
        #pragma unroll
        for (int r = 0; r < R; ++r) acc[r] = 0.0f;
        for (int k = 0; k < D; ++k) {
            float w = W[d * D + k];
            #pragma unroll
            for (int r = 0; r < R; ++r) acc[r] += xs[r * D + k] * w;
        }
        #pragma unroll
        for (int r = 0; r < R; ++r) out[(r0 + r) * D + d] = acc[r];
    }
}

// ---------------- causal attention: 2 queries/lane, 128-q blocks ----------------
__global__ __launch_bounds__(512) void k_attn(const float* __restrict__ qkv,
                                              float* __restrict__ ao) {
    __shared__ float Ks[128][12];
    __shared__ float Vs[128][12];
    __shared__ float cmb[64][8][12];
    int h = blockIdx.y;
    int qb = 15 - blockIdx.x;          // long blocks dispatched first
    int q0 = qb * 128;
    int t = threadIdx.x;
    int i = t & 63, w = t >> 6;
    int qiL = q0 + i, qiH = q0 + 64 + i;
    const float* kp = qkv + S * D + h * DKH;
    const float* vp = qkv + 2 * S * D + h * DKH;
    float qL[DKH], qH[DKH];
    #pragma unroll
    for (int c = 0; c < DKH; ++c) {
        qL[c] = qkv[qiL * D + h * DKH + c];
        qH[c] = qkv[qiH * D + h * DKH + c];
    }
    float mL = -INFINITY, lL = 0.0f, aL[DKH] = {};
    float mH = -INFINITY, lH = 0.0f, aH[DKH] = {};
    const float scale = 0.31622776601683794f;  // 1/sqrt(10)
    int ntiles = qb + 1;
    for (int tile = 0; tile < ntiles; ++tile) {
        int j0 = tile << 7;
        __syncthreads();
        for (int idx = t; idx < 128 * DKH; idx += 512) {
            int jj = idx / DKH, c = idx - jj * DKH;
            Ks[jj][c] = kp[(j0 + jj) * D + c];
            Vs[jj][c] = vp[(j0 + jj) * D + c];
        }
        __syncthreads();
        float svL[16], svH[16], tmL = -INFINITY, tmH = -INFINITY;
        #pragma unroll
        for (int u = 0; u < 16; ++u) {
            int jj = w * 16 + u;
            int j = j0 + jj;
            float kc[DKH];
            #pragma unroll
            for (int c = 0; c < DKH; ++c) kc[c] = Ks[jj][c];
            float dL = 0.0f, dH = 0.0f;
            #pragma unroll
            for (int c = 0; c < DKH; ++c) { dL += qL[c] * kc[c]; dH += qH[c] * kc[c]; }
            svL[u] = (j <= qiL) ? dL * scale : -INFINITY;
            svH[u] = (j <= qiH) ? dH * scale : -INFINITY;
            tmL = fmaxf(tmL, svL[u]);
            tmH = fmaxf(tmH, svH[u]);
        }
        bool doL = (tmL > -INFINITY), doH = (tmH > -INFINITY);
        if (doL) {
            float nm = fmaxf(mL, tmL);
            float cor = __expf(mL - nm);
            lL *= cor;
            #pragma unroll
            for (int c = 0; c < DKH; ++c) aL[c] *= cor;
            mL = nm;
        }
        if (doH) {
            float nm = fmaxf(mH, tmH);
            float cor = __expf(mH - nm);
            lH *= cor;
            #pragma unroll
            for (int c = 0; c < DKH; ++c) aH[c] *= cor;
            mH = nm;
        }
        if (doL || doH) {
            #pragma unroll
            for (int u = 0; u < 16; ++u) {
                int jj = w * 16 + u;
                float pL = doL ? __expf(svL[u] - mL) : 0.0f;
                float pH = doH ? __expf(svH[u] - mH) : 0.0f;
                lL += pL; lH += pH;
                #pragma unroll
                for (int c = 0; c < DKH; ++c) {
                    float vv = Vs[jj][c];
                    aL[c] += pL * vv;
                    aH[c] += pH * vv;
                }
            }
        }
    }
    // combine low queries
    __syncthreads();
    cmb[i][w][0] = mL; cmb[i][w][1] = lL;
    #pragma unroll
    for (int c = 0; c < DKH; ++c) cmb[i][w][2 + c] = aL[c];
    __syncthreads();
    if (t < 64) {
        float M = -INFINITY;
        for (int ww = 0; ww < 8; ++ww) M = fmaxf(M, cmb[t][ww][0]);
        float L = 0.0f, o[DKH] = {};
        for (int ww = 0; ww < 8; ++ww) {
            float e = __expf(cmb[t][ww][0] - M);
            L += e * cmb[t][ww][1];
            #pragma unroll
            for (int c = 0; c < DKH; ++c) o[c] += e * cmb[t][ww][2 + c];
        }
        float inv = 1.0f / L;
        float* op = ao + (q0 + t) * D + h * DKH;
        #pragma unroll
        for (int c = 0; c < DKH; ++c) op[c] = o[c] * inv;
    }
    // combine high queries
    __syncthreads();
    cmb[i][w][0] = mH; cmb[i][w][1] = lH;
    #pragma unroll
    for (int c = 0; c < DKH; ++c) cmb[i][w][2 + c] = aH[c];
    __syncthreads();
    if (t < 64) {
        float M = -INFINITY;
        for (int ww = 0; ww < 8; ++ww) M = fmaxf(M, cmb[t][ww][0]);
        float L = 0.0f, o[DKH] = {};
        for (int ww = 0; ww < 8; ++ww) {
            float e = __expf(cmb[t][ww][0] - M);
            L += e * cmb[t][ww][1];
            #pragma unroll
            for (int c = 0; c < DKH; ++c) o[c] += e * cmb[t][ww][2 + c];
        }
        float inv = 1.0f / L;
        float* op = ao + (q0 + 64 + t) * D + h * DKH;
        #pragma unroll
        for (int c = 0; c < DKH; ++c) op[c] = o[c] * inv;
    }
}

// ---------------- wave helpers ----------------
__device__ inline float wave_sum(float v) {
    #pragma unroll
    for (int o = 32; o > 0; o >>= 1) v += __shfl_xor(v, o);
    return v;
}

// ---------------- LayerNorm 1: x1 = LN(x0 + ao)*g + b ----------------
__global__ void k_ln1(const float* __restrict__ x0, const float* __restrict__ ao,
                      const float* __restrict__ g, const float* __restrict__ b,
                      float* __restrict__ x1) {
    int row = blockIdx.x * 4 + (threadIdx.x >> 6);
    int lane = threadIdx.x & 63;
    const float* pa = x0 + row * D;
    const float* pb = ao + row * D;
    float v[3];
    int c[3];
    float sum = 0.0f;
    #pragma unroll
    for (int k = 0; k < 3; ++k) {
        c[k] = lane + 64 * k;
        v[k] = (c[k] < D) ? (pa[c[k]] + pb[c[k]]) : 0.0f;
        sum += v[k];
    }
    sum = wave_sum(sum);
    float mu = sum / (float)D;
    float ss = 0.0f;
    #pragma unroll
    for (int k = 0; k < 3; ++k) {
        float dd = (c[k] < D) ? (v[k] - mu) : 0.0f;
        ss += dd * dd;
    }
    ss = wave_sum(ss);
    float rs = rsqrtf(ss / (float)D + EPS);
    #pragma unroll
    for (int k = 0; k < 3; ++k)
        if (c[k] < D) x1[row * D + c[k]] = (v[k] - mu) * rs * g[c[k]] + b[c[k]];
}

// ---------------- FFN1: y = gelu(x1 @ W1^T + bf1) ----------------
__global__ void k_ffn1(const float* __restrict__ x1, const float* __restrict__ W1,
                       const float* __restrict__ bf1, float* __restrict__ y) {
    const int R = 16;
    __shared__ float xs[R * D];
    int r0 = blockIdx.y * R;
    int f = blockIdx.x * 256 + threadIdx.x;
    for (int idx = threadIdx.x; idx < R * D; idx += 256)
        xs[idx] = x1[r0 * D + idx];
    __syncthreads();
    if (f < F) {
        float acc[R] = {};
        for (int k = 0; k < D; ++k) {
            float wv = W1[f * D + k];
            #pragma unroll
            for (int r = 0; r < R; ++r) acc[r] += xs[r * D + k] * wv;
        }
        float bb = bf1[f];
        #pragma unroll
        for (int r = 0; r < R; ++r) {
            float vv = acc[r] + bb;
            float gg = 0.5f * vv * (1.0f + erff(vv * 0.7071067811865475f));
            y[(r0 + r) * F + f] = gg;
        }
    }
}

// ---------------- FFN2 + LN2 fused: xb = bf16(LN(x1 + y@W2^T + bf2)) ----------------
__global__ void k_ffn2ln(const float* __restrict__ y, const float* __restrict__ W2,
                         const float* __restrict__ bf2, const float* __restrict__ x1,
                         const float* __restrict__ g, const float* __restrict__ b,
                         __hip_bfloat16* __restrict__ xb) {
    const int R = 4;
    __shared__ float ys[R * F];
    __shared__ float red[2][3][R];
    int r0 = blockIdx.x * R;
    for (int idx = threadIdx.x; idx < R * F; idx += 192)
        ys[idx] = y[r0 * F + idx];
    __syncthreads();
    int d = threadIdx.x;           // 0..191
    int w = d >> 6, lane = d & 63;
    float v[R];
    #pragma unroll
    for (int r = 0; r < R; ++r) v[r] = 0.0f;
    if (d < D) {
        float acc[R] = {};
        for (int k = 0; k < F; ++k) {
            float wv = W2[d * F + k];
            #pragma unroll
            for (int r = 0; r < R; ++r) acc[r] += ys[r * F + k] * wv;
        }
        #pragma unroll
        for (int r = 0; r < R; ++r)
            v[r] = x1[(r0 + r) * D + d] + acc[r] + bf2[d];
    }
    #pragma unroll
    for (int r = 0; r < R; ++r) {
        float s1 = wave_sum(v[r]);
        float s2 = wave_sum(v[r] * v[r]);
        if (lane == 0) { red[0][w][r] = s1; red[1][w][r] = s2; }
    }
    __syncthreads();
    #pragma unroll
    for (int r = 0; r < R; ++r) {
        float sum = red[0][0][r] + red[0][1][r] + red[0][2][r];
        float sq  = red[1][0][r] + red[1][1][r] + red[1][2][r];
        float mu = sum / (float)D;
        float var = sq / (float)D - mu * mu;
        float rs = rsqrtf(var + EPS);
        float outv = (d < D) ? ((v[r] - mu) * rs * g[d] + b[d]) : 0.0f;
        xb[(r0 + r) * KP + d] = __float2bfloat16(outv);
    }
}

// ---------------- logits GEMM: out = xb @ wb^T + bo ----------------
// swapped-operand MFMA; epilogue via per-wave LDS transpose -> aligned coalesced
// dword stores (256B contiguous per instruction). No unaligned wide stores.
// grid 6288 = 16 (M/128) * 393 (VP/128); block 256 = 4 waves (2x2), 64x64 per wave
__global__ void k_logits(const __hip_bfloat16* __restrict__ xbp,
                         const __hip_bfloat16* __restrict__ wbp,
                         const float* __restrict__ bo, float* __restrict__ out) {
    __shared__ float stg[4][16][68];       // 68-float stride: 16B aligned rows, conflict-free reads
    int Lb = blockIdx.x;
    int wg = (Lb & 7) * 786 + (Lb >> 3);   // bijective XCD swizzle (6288 = 8*786)
    int mblk = wg & 15;
    int pblk = wg >> 4;
    int m0 = mblk * 128, n0 = pblk * 128;
    int t = threadIdx.x;
    int lane = t & 63, wid = t >> 6;
    int wy = wid >> 1, wx = wid & 1;
    int r16 = lane & 15, kg = lane >> 4;
    const short* xs = (const short*)xbp;
    const short* ws = (const short*)wbp;
    f32x4 acc[4][4] = {};
    int mrow[4], nrow[4];
    #pragma unroll
    for (int mi = 0; mi < 4; ++mi) mrow[mi] = m0 + wy * 64 + mi * 16 + r16;
    #pragma unroll
    for (int ni = 0; ni < 4; ++ni) nrow[ni] = n0 + wx * 64 + ni * 16 + r16;
    #pragma unroll
    for (int kk = 0; kk < 6; ++kk) {
        int kb = kk * 32 + kg * 8;
        bf16x8 a[4], bfr[4];
        #pragma unroll
        for (int mi = 0; mi < 4; ++mi)
            a[mi] = *(const bf16x8*)(xs + mrow[mi] * KP + kb);
        #pragma unroll
        for (int ni = 0; ni < 4; ++ni)
            bfr[ni] = *(const bf16x8*)(ws + nrow[ni] * KP + kb);
        #pragma unroll
        for (int mi = 0; mi < 4; ++mi)
            #pragma unroll
            for (int ni = 0; ni < 4; ++ni)
                acc[mi][ni] = __builtin_amdgcn_mfma_f32_16x16x32_bf16(bfr[ni], a[mi], acc[mi][ni], 0, 0, 0);
    }
    // lane holds out[m0+wy*64+mi*16+r16][n0+wx*64+ni*16+kg*4 + j], j=0..3
    int colbase = n0 + wx * 64;
    #pragma unroll
    for (int mi = 0; mi < 4; ++mi) {
        __syncthreads();
        #pragma unroll
        for (int ni = 0; ni < 4; ++ni) {
            int cn = colbase + ni * 16 + kg * 4;
            f32x4 r = acc[mi][ni];
            #pragma unroll
            for (int j = 0; j < 4; ++j) r[j] += (cn + j < V) ? bo[cn + j] : 0.0f;
            *(f32x4*)&stg[wid][r16][ni * 16 + kg * 4] = r;
        }
        __syncthreads();
        int row = m0 + wy * 64 + mi * 16;
        int col = colbase + lane;
        bool ok = (col < V);
        #pragma unroll
        for (int rr = 0; rr < 16; ++rr) {
            float val = stg[wid][rr][lane];
            if (ok) out[(size_t)(row + rr) * V + col] = val;
        }
    }
}

extern "C" void kernel_launch(void* const* d_in, const int* in_sizes, int n_in,
                              void* d_out, int out_size, void* d_ws, size_t ws_size,
                              hipStream_t stream) {
    const int* ids   = (const int*)d_in[0];
    const float* emb = (const float*)d_in[1];
    const float* Wq  = (const float*)d_in[2];
    const float* Wk  = (const float*)d_in[3];
    const float* Wv  = (const float*)d_in[4];
    const float* g1  = (const float*)d_in[5];
    const float* b1  = (const float*)d_in[6];
    const float* W1  = (const float*)d_in[7];
    const float* bf1 = (const float*)d_in[8];
    const float* W2  = (const float*)d_in[9];
    const float* bf2 = (const float*)d_in[10];
    const float* g2  = (const float*)d_in[11];
    const float* b2  = (const float*)d_in[12];
    const float* Wo  = (const float*)d_in[13];
    const float* bo  = (const float*)d_in[14];
    float* out = (float*)d_out;

    char* w = (char*)d_ws;
    float* x0 = (float*)w;           w += S * D * 4;
    float* qkv = (float*)w;          w += 3 * S * D * 4;
    float* ao = (float*)w;           w += S * D * 4;
    float* x1 = (float*)w;           w += S * D * 4;
    float* y = (float*)w;            w += S * F * 4;
    __hip_bfloat16* xb = (__hip_bfloat16*)w; w += S * KP * 2;
    __hip_bfloat16* wb = (__hip_bfloat16*)w; w += (size_t)VP * KP * 2;

    k_wbconv<<<dim3((VP * 24 + 255) / 256), 256, 0, stream>>>(Wo, wb);
    k_embed<<<dim3(S), 192, 0, stream>>>(ids, emb, x0);
    k_qkv<<<dim3(S / 8, 3), 192, 0, stream>>>(x0, Wq, Wk, Wv, qkv);
    k_attn<<<dim3(16, H), 512, 0, stream>>>(qkv, ao);
    k_ln1<<<dim3(S / 4), 256, 0, stream>>>(x0, ao, g1, b1, x1);
    k_ffn1<<<dim3(3, S / 16), 256, 0, stream>>>(x1, W1, bf1, y);
    k_ffn2ln<<<dim3(S / 4), 192, 0, stream>>>(y, W2, bf2, x1, g2, b2, xb);
    k_logits<<<dim3(6288), 256, 0, stream>>>(xb, wb, bo, out);
}